// Round 7
// baseline (2265.997 us; speedup 1.0000x reference)
//
#include <hip/hip_runtime.h>

typedef __bf16 bf16;
typedef bf16 bf16x8 __attribute__((ext_vector_type(8)));
typedef float f32x4 __attribute__((ext_vector_type(4)));

#define NB 256     // batch
#define TS 64      // timesteps
#define DD 1024    // input dim
#define HH 1024    // hidden
#define NOUT 4096  // 4H
#define K2 2048    // step-GEMM K: [h | attn]
#define K2TILES 64 // K2/32
#define KGITERS 8  // per K-group: 512/64

// Fragment tiles: 16col x 32k of 512 bf16 (1 KB); element (l,j):
// col = base+(l&15), k = kbase+(l>>4)*8+j  (matches mfma_16x16x32 operands;
// global_load_lds staging is the exact linear lane*16B placement).
// W2t ([Wh;Wattn], 2048x4096) is gate-interleaved: tile tau covers original
// column (tau&3)*1024 + (tau>>2)*16 + (l&15) -> wg owning 16 h x 4 gates
// finishes the LSTM cell locally. Wxt (1024x4096) keeps ORIGINAL col order.
// Aop (256 x 2048 = [h|attn]) row-major bf16, double-buffered by parity.

static __device__ __forceinline__ void gload_lds16(const void* g, void* l) {
  __builtin_amdgcn_global_load_lds(
      (const __attribute__((address_space(1))) void*)g,
      (__attribute__((address_space(3))) void*)l, 16, 0, 0);
}

// ---- one-time converts -----------------------------------------------------
__global__ __launch_bounds__(256) void convert_x(const float* __restrict__ x,
                                                 bf16* __restrict__ x_bf) {
  const int gid = blockIdx.x * 256 + threadIdx.x;  // 8 elems each
  bf16x8 o;
#pragma unroll
  for (int j = 0; j < 8; ++j) o[j] = (bf16)x[(size_t)gid * 8 + j];
  *(bf16x8*)(x_bf + (size_t)gid * 8) = o;
}

__global__ __launch_bounds__(256) void convert_wx(const float* __restrict__ Wx,
                                                  bf16* __restrict__ Wxt) {
  const int gid = blockIdx.x * 256 + threadIdx.x;
  const int tile = gid >> 6, l = gid & 63;      // tile = nt*32 + kt
  const int nt = tile >> 5, kt = tile & 31;
  const int col = nt * 16 + (l & 15);
  const int k0 = kt * 32 + (l >> 4) * 8;
  bf16x8 o;
#pragma unroll
  for (int j = 0; j < 8; ++j) o[j] = (bf16)Wx[(size_t)(k0 + j) * NOUT + col];
  *(bf16x8*)(Wxt + (size_t)tile * 512 + l * 8) = o;
}

__global__ __launch_bounds__(256) void convert_w2(const float* __restrict__ Wh,
                                                  const float* __restrict__ Wattn,
                                                  bf16* __restrict__ W2t) {
  const int gid = blockIdx.x * 256 + threadIdx.x;
  const int tile = gid >> 6, l = gid & 63;      // tile = tau*64 + kt
  const int tau = tile >> 6, kt = tile & 63;
  const int col = (tau & 3) * 1024 + (tau >> 2) * 16 + (l & 15);
  const int k0 = kt * 32 + (l >> 4) * 8;
  bf16x8 o;
#pragma unroll
  for (int j = 0; j < 8; ++j) {
    const int k = k0 + j;
    o[j] = (bf16)((k < HH) ? Wh[(size_t)k * NOUT + col]
                           : Wattn[(size_t)(k - HH) * NOUT + col]);
  }
  *(bf16x8*)(W2t + (size_t)tile * 512 + l * 8) = o;
}

// ---- one-time xWx = x @ Wx (16384 x 4096, bf16 out) ------------------------
// 64x64 tile, 4 waves (2x2 of 32x32), K=1024, A via global_load_lds dbuf.
__global__ __launch_bounds__(256) void xgemm(const bf16* __restrict__ x_bf,
                                             const bf16* __restrict__ Wxt,
                                             bf16* __restrict__ xWx) {
  __shared__ __align__(16) bf16 astg[2][8 * 512];  // 16 KB
  const int b = blockIdx.x;
  const int ct = b & 63, rt = b >> 6;  // rt [0,256): 64 rows; ct [0,64): 64 cols
  const int tid = threadIdx.x, lane = tid & 63, wid = tid >> 6;
  const int wr = wid >> 1, wc = wid & 1;

  // A staging: wave stages tiles tl = wid*2+e (mt=tl>>1, kk=tl&1)
  const bf16* gA[2];
  int ldsA[2];
#pragma unroll
  for (int e = 0; e < 2; ++e) {
    const int tl = wid * 2 + e, mt = tl >> 1, kk = tl & 1;
    gA[e] = x_bf + (size_t)(rt * 64 + mt * 16 + (lane & 15)) * DD + kk * 32 + (lane >> 4) * 8;
    ldsA[e] = tl * 512;
  }
  // B: taus ct*4 + wc*2 + j, original-order Wxt (32 ktiles per tau)
  const bf16* gB[2][2];
#pragma unroll
  for (int j = 0; j < 2; ++j)
#pragma unroll
    for (int kk = 0; kk < 2; ++kk)
      gB[j][kk] = Wxt + ((size_t)(ct * 4 + wc * 2 + j) * 32 + kk) * 512 + lane * 8;

  f32x4 acc[2][2];
#pragma unroll
  for (int i = 0; i < 2; ++i)
#pragma unroll
    for (int j = 0; j < 2; ++j) acc[i][j] = (f32x4){0, 0, 0, 0};

#pragma unroll
  for (int e = 0; e < 2; ++e) gload_lds16(gA[e], &astg[0][ldsA[e]]);
  bf16x8 bc[2][2];
#pragma unroll
  for (int j = 0; j < 2; ++j)
#pragma unroll
    for (int kk = 0; kk < 2; ++kk) bc[j][kk] = *(const bf16x8*)gB[j][kk];

  for (int it = 0; it < 16; ++it) {
    __syncthreads();
    bf16x8 bn[2][2];
    if (it < 15) {
#pragma unroll
      for (int e = 0; e < 2; ++e)
        gload_lds16(gA[e] + (it + 1) * 64, &astg[(it + 1) & 1][ldsA[e]]);
#pragma unroll
      for (int j = 0; j < 2; ++j)
#pragma unroll
        for (int kk = 0; kk < 2; ++kk)
          bn[j][kk] = *(const bf16x8*)(gB[j][kk] + (it + 1) * 1024);
    }
    const bf16* abuf = astg[it & 1];
#pragma unroll
    for (int kk = 0; kk < 2; ++kk) {
      const bf16x8 a0 = *(const bf16x8*)(abuf + ((wr * 2 + 0) * 2 + kk) * 512 + lane * 8);
      const bf16x8 a1 = *(const bf16x8*)(abuf + ((wr * 2 + 1) * 2 + kk) * 512 + lane * 8);
      acc[0][0] = __builtin_amdgcn_mfma_f32_16x16x32_bf16(a0, bc[0][kk], acc[0][0], 0, 0, 0);
      acc[0][1] = __builtin_amdgcn_mfma_f32_16x16x32_bf16(a0, bc[1][kk], acc[0][1], 0, 0, 0);
      acc[1][0] = __builtin_amdgcn_mfma_f32_16x16x32_bf16(a1, bc[0][kk], acc[1][0], 0, 0, 0);
      acc[1][1] = __builtin_amdgcn_mfma_f32_16x16x32_bf16(a1, bc[1][kk], acc[1][1], 0, 0, 0);
    }
    if (it < 15) {
#pragma unroll
      for (int j = 0; j < 2; ++j)
#pragma unroll
        for (int kk = 0; kk < 2; ++kk) bc[j][kk] = bn[j][kk];
    }
  }
  // epilogue: col=lane&15, row=(lane>>4)*4+r [m89-verified]
#pragma unroll
  for (int i = 0; i < 2; ++i)
#pragma unroll
    for (int j = 0; j < 2; ++j) {
      const int row0 = rt * 64 + wr * 32 + i * 16 + (lane >> 4) * 4;
      const int col = ct * 64 + wc * 32 + j * 16 + (lane & 15);
#pragma unroll
      for (int r = 0; r < 4; ++r)
        xWx[(size_t)(row0 + r) * NOUT + col] = (bf16)acc[i][j][r];
    }
}

// ---- attention tail (R3-proven) --------------------------------------------
static __device__ __forceinline__ void attn_tail(
    int n, int u, const float* __restrict__ A, bf16* __restrict__ Aop,
    const float* __restrict__ h_sh, float* __restrict__ scA,
    float* __restrict__ scB) {
  const int lane = u & 63, w = u >> 6;
  const float* ap = A + (size_t)n * (HH * 16) + w;  // position p = w
  float s = 0.f;
#pragma unroll
  for (int i = 0; i < 16; ++i) {
    const int idx = lane + 64 * i;
    s = fmaf(h_sh[idx], ap[(size_t)idx * 16], s);
  }
  s += __int_as_float(__builtin_amdgcn_ds_swizzle(__float_as_int(s), 0x041F));
  s += __int_as_float(__builtin_amdgcn_ds_swizzle(__float_as_int(s), 0x081F));
  s += __int_as_float(__builtin_amdgcn_ds_swizzle(__float_as_int(s), 0x101F));
  s += __int_as_float(__builtin_amdgcn_ds_swizzle(__float_as_int(s), 0x201F));
  s += __int_as_float(__builtin_amdgcn_ds_swizzle(__float_as_int(s), 0x401F));
  if (lane == 0) scA[w] = s;
  else if (lane == 32) scB[w] = s;
  __syncthreads();
  float e[16];
  float m = -3.0e38f;
#pragma unroll
  for (int p = 0; p < 16; ++p) {
    e[p] = (scA[p] + scB[p]) * 0.03125f;  // 1/sqrt(1024)
    m = fmaxf(m, e[p]);
  }
  float sum = 0.f;
#pragma unroll
  for (int p = 0; p < 16; ++p) {
    e[p] = expf(e[p] - m);
    sum += e[p];
  }
  const float inv = 1.f / sum;
  const float* arow = A + (size_t)n * (HH * 16) + (size_t)u * 16;
  float av = 0.f;
#pragma unroll
  for (int p = 0; p < 16; ++p) av = fmaf(arow[p], e[p], av);
  Aop[(size_t)n * K2 + HH + u] = (bf16)(av * inv);  // attn cols [1024,2048)
}

// h0 = mean(A); c0 = h0; pack [h0 | attn0] into Aop buffer 0.
__global__ __launch_bounds__(1024) void init_kernel(const float* __restrict__ A,
                                                    float* __restrict__ c_ws,
                                                    bf16* __restrict__ Aop) {
  __shared__ float h_sh[HH];
  __shared__ float scA[16], scB[16];
  const int n = (blockIdx.x & 7) * 32 + (blockIdx.x >> 3);
  const int u = threadIdx.x;
  const float* arow = A + (size_t)n * (HH * 16) + (size_t)u * 16;
  float h0 = 0.f;
#pragma unroll
  for (int p = 0; p < 16; ++p) h0 += arow[p];
  h0 *= 0.0625f;
  c_ws[n * HH + u] = h0;
  h_sh[u] = h0;
  Aop[(size_t)n * K2 + u] = (bf16)h0;
  __syncthreads();
  attn_tail(n, u, A, Aop, h_sh, scA, scB);
}

// attn for step t+1: reads h_ws, writes Aop_nxt attn cols. XCD-pinned n.
__global__ __launch_bounds__(1024) void attn_kernel(const float* __restrict__ h_ws,
                                                    const float* __restrict__ A,
                                                    bf16* __restrict__ Aop_nxt) {
  __shared__ float h_sh[HH];
  __shared__ float scA[16], scB[16];
  const int n = (blockIdx.x & 7) * 32 + (blockIdx.x >> 3);
  const int u = threadIdx.x;
  h_sh[u] = h_ws[n * HH + u];
  __syncthreads();
  attn_tail(n, u, A, Aop_nxt, h_sh, scA, scB);
}

// ---------------------------------------------------------------------------
// Fused step-GEMM + LSTM cell. wg (rt, ht): 64 n x (16 h x 4 gates = 64 cols).
// 16 waves = 4 K-groups (K=512) x 4 out-waves (2x2 of 32x32).
// A: global_load_lds dbuf; B: direct global->reg with 1-iter prefetch.
// K-group partials reduced via LDS; cell (incl. precomputed xWx) local.
// ---------------------------------------------------------------------------
#define SMEM_BYTES 69632  // max(A-staging 65536, red 4*64*68*4 = 69632)

__global__ __launch_bounds__(1024, 4) void gemm_cell(
    const bf16* __restrict__ Aop_cur, bf16* __restrict__ Aop_nxt,
    const bf16* __restrict__ W2t, const bf16* __restrict__ xWx,
    const float* __restrict__ bias, float* __restrict__ c_ws,
    float* __restrict__ h_ws, float* __restrict__ out, const int t) {
  __shared__ __align__(16) char smem[SMEM_BYTES];
  bf16* astg = (bf16*)smem;   // [kg][buf][tl 0..8][512] = 64 KB
  float* red = (float*)smem;  // [kg][c 0..64][68] f32 (union after K-loop)

  const int b = blockIdx.x;
  const int xcd = b & 7, idx = b >> 3;
  const int ht = xcd * 8 + (idx & 7);  // [0,64): h-group [ht*16, +16), 4 gates
  const int rt = idx >> 3;             // [0,4):  n-range [rt*64, +64)
  const int tid = threadIdx.x, lane = tid & 63, wid = tid >> 6;
  const int kg = wid >> 2;             // K in [kg*512, +512)
  const int ow = wid & 3, wr = ow >> 1, wc = ow & 1;

  // A staging: wave stages tiles tl = ow*2+e of its kg (mt=tl>>1, kk=tl&1)
  const bf16* gA[2];
  int ldsA[2];
#pragma unroll
  for (int e = 0; e < 2; ++e) {
    const int tl = ow * 2 + e, mt = tl >> 1, kk = tl & 1;
    gA[e] = Aop_cur + (size_t)(rt * 64 + mt * 16 + (lane & 15)) * K2 +
            kg * 512 + kk * 32 + (lane >> 4) * 8;
    ldsA[e] = (kg * 2) * 8 * 512 + tl * 512;  // + buf*4096
  }
  // B: taus ht*4 + wc*2 + j (gate-interleaved W2t), ktile base kg*16
  const bf16* gB[2][2];
#pragma unroll
  for (int j = 0; j < 2; ++j)
#pragma unroll
    for (int kk = 0; kk < 2; ++kk)
      gB[j][kk] = W2t + ((size_t)(ht * 4 + wc * 2 + j) * K2TILES + kg * 16 + kk) * 512 + lane * 8;

  f32x4 acc[2][2];
#pragma unroll
  for (int i = 0; i < 2; ++i)
#pragma unroll
    for (int j = 0; j < 2; ++j) acc[i][j] = (f32x4){0, 0, 0, 0};

#pragma unroll
  for (int e = 0; e < 2; ++e) gload_lds16(gA[e], astg + ldsA[e]);
  bf16x8 bc[2][2];
#pragma unroll
  for (int j = 0; j < 2; ++j)
#pragma unroll
    for (int kk = 0; kk < 2; ++kk) bc[j][kk] = *(const bf16x8*)gB[j][kk];

  for (int it = 0; it < KGITERS; ++it) {
    __syncthreads();  // buf(it&1) staged (vmcnt drained); prev readers done
    bf16x8 bn[2][2];
    if (it < KGITERS - 1) {
#pragma unroll
      for (int e = 0; e < 2; ++e)
        gload_lds16(gA[e] + (it + 1) * 64, astg + ldsA[e] + ((it + 1) & 1) * 4096);
#pragma unroll
      for (int j = 0; j < 2; ++j)
#pragma unroll
        for (int kk = 0; kk < 2; ++kk)
          bn[j][kk] = *(const bf16x8*)(gB[j][kk] + (it + 1) * 1024);
    }
    const bf16* abuf = astg + (kg * 2 + (it & 1)) * 8 * 512;
#pragma unroll
    for (int kk = 0; kk < 2; ++kk) {
      const bf16x8 a0 = *(const bf16x8*)(abuf + ((wr * 2 + 0) * 2 + kk) * 512 + lane * 8);
      const bf16x8 a1 = *(const bf16x8*)(abuf + ((wr * 2 + 1) * 2 + kk) * 512 + lane * 8);
      acc[0][0] = __builtin_amdgcn_mfma_f32_16x16x32_bf16(a0, bc[0][kk], acc[0][0], 0, 0, 0);
      acc[0][1] = __builtin_amdgcn_mfma_f32_16x16x32_bf16(a0, bc[1][kk], acc[0][1], 0, 0, 0);
      acc[1][0] = __builtin_amdgcn_mfma_f32_16x16x32_bf16(a1, bc[0][kk], acc[1][0], 0, 0, 0);
      acc[1][1] = __builtin_amdgcn_mfma_f32_16x16x32_bf16(a1, bc[1][kk], acc[1][1], 0, 0, 0);
    }
    if (it < KGITERS - 1) {
#pragma unroll
      for (int j = 0; j < 2; ++j)
#pragma unroll
        for (int kk = 0; kk < 2; ++kk) bc[j][kk] = bn[j][kk];
    }
  }

  __syncthreads();  // all astg reads consumed: red region live

  // frag store: within-tile col c = wc*32 + j*16 + (lane&15); n = wr*32 + i*16
  // + (lane>>4)*4 + r.  red[(kg*64 + c)*68 + n]  (68%4==0: f32x4 aligned)
#pragma unroll
  for (int i = 0; i < 2; ++i)
#pragma unroll
    for (int j = 0; j < 2; ++j) {
      const int c = wc * 32 + j * 16 + (lane & 15);
      const int nn = wr * 32 + i * 16 + (lane >> 4) * 4;
      *(f32x4*)&red[(kg * 64 + c) * 68 + nn] = acc[i][j];
    }
  __syncthreads();

  // cell: thread (nloc = tid>>4, hl = tid&15); gate g at c = g*16 + hl
  {
    const int nloc = tid >> 4, hl = tid & 15;
    const int n = rt * 64 + nloc;
    const int h = ht * 16 + hl;
    float gate[4];
#pragma unroll
    for (int g = 0; g < 4; ++g) {
      float v = bias[g * HH + h] + (float)xWx[((size_t)n * TS + t) * NOUT + g * HH + h];
#pragma unroll
      for (int k = 0; k < 4; ++k) v += red[(k * 64 + g * 16 + hl) * 68 + nloc];
      gate[g] = v;
    }
    const float cold = c_ws[n * HH + h];
    const float si = 1.f / (1.f + expf(-gate[0]));
    const float sf = 1.f / (1.f + expf(-gate[1]));
    const float so = 1.f / (1.f + expf(-gate[2]));
    const float cn = sf * cold + si * tanhf(gate[3]);
    const float hn = so * tanhf(cn);
    c_ws[n * HH + h] = cn;
    out[((size_t)n * TS + t) * HH + h] = hn;
    h_ws[n * HH + h] = hn;
    if (t < TS - 1) Aop_nxt[(size_t)n * K2 + h] = (bf16)hn;
  }
}

// ---------------------------------------------------------------------------
// ws layout (bytes):
//   [0, 16777216)             W2t   bf16 gate-tiled [Wh;Wattn] (2048x4096)
//   [16777216, 25165824)      Wxt   bf16 tiled Wx (1024x4096, original cols)
//   [25165824, 58720256)      x_bf  bf16 row-major x (16384 x 1024)
//   [58720256, 192937984)     xWx   bf16 (16384 x 4096)
//   [192937984, 193986560)    Aop0  bf16 (256 x 2048)
//   [193986560, 195035136)    Aop1  bf16 (256 x 2048)
//   [195035136, 196083712)    c_ws  f32 (256 x 1024)
//   [196083712, 197132288)    h_ws  f32 (256 x 1024)
// total ~197 MB (ws = 256 MiB per harness poison fill)
// ---------------------------------------------------------------------------
extern "C" void kernel_launch(void* const* d_in, const int* in_sizes, int n_in,
                              void* d_out, int out_size, void* d_ws, size_t ws_size,
                              hipStream_t stream) {
  const float* x     = (const float*)d_in[0];
  const float* A     = (const float*)d_in[1];
  const float* Wx    = (const float*)d_in[2];
  const float* Wh    = (const float*)d_in[3];
  const float* Wattn = (const float*)d_in[4];
  const float* bias  = (const float*)d_in[5];
  float* out = (float*)d_out;
  char* ws = (char*)d_ws;
  bf16* W2t    = (bf16*)(ws + 0);
  bf16* Wxt    = (bf16*)(ws + 16777216);
  bf16* x_bf   = (bf16*)(ws + 25165824);
  bf16* xWx    = (bf16*)(ws + 58720256);
  bf16* Aop[2] = {(bf16*)(ws + 192937984), (bf16*)(ws + 193986560)};
  float* c_ws  = (float*)(ws + 195035136);
  float* h_ws  = (float*)(ws + 196083712);

  convert_x<<<8192, 256, 0, stream>>>(x, x_bf);
  convert_wx<<<2048, 256, 0, stream>>>(Wx, Wxt);
  convert_w2<<<4096, 256, 0, stream>>>(Wh, Wattn, W2t);
  xgemm<<<16384, 256, 0, stream>>>(x_bf, Wxt, xWx);
  init_kernel<<<NB, 1024, 0, stream>>>(A, c_ws, Aop[0]);
  for (int t = 0; t < TS; ++t) {
    gemm_cell<<<NB, 1024, 0, stream>>>(Aop[t & 1], Aop[(t + 1) & 1], W2t, xWx,
                                       bias, c_ws, h_ws, out, t);
    if (t < TS - 1)
      attn_kernel<<<NB, 1024, 0, stream>>>(h_ws, A, Aop[(t + 1) & 1]);
  }
}

// Round 8
// 2096.335 us; speedup vs baseline: 1.0809x; 1.0809x over previous
//
#include <hip/hip_runtime.h>

typedef __bf16 bf16;
typedef bf16 bf16x8 __attribute__((ext_vector_type(8)));
typedef bf16 bf16x4 __attribute__((ext_vector_type(4)));
typedef float f32x4 __attribute__((ext_vector_type(4)));

#define NB 256
#define TS 64
#define DD 1024
#define HH 1024
#define NOUT 4096

// Column permutation (all weight/preact tensors): cx = (h>>4)*64 + (h&15)*4 + g
// where original col co = g*1024 + h. wg "ht" owns cx in [ht*64, ht*64+64) =
// {16 h} x {4 gates} -> finishes the LSTM cell locally; cell thread (n,hl)
// reads its 4 gates as ONE vector at offset ht*64 + hl*4.
// Fragment tiles: 16col x 32k of 512 bf16; element (l,j): col=base+(l&15),
// k=kbase+(l>>4)*8+j (mfma_16x16x32 operand layout; linear LDS staging).

static __device__ __forceinline__ void gload_lds16(const void* g, void* l) {
  __builtin_amdgcn_global_load_lds(
      (const __attribute__((address_space(1))) void*)g,
      (__attribute__((address_space(3))) void*)l, 16, 0, 0);
}

#define SWZ_ADD(v, imm) \
  (v) += __int_as_float(__builtin_amdgcn_ds_swizzle(__float_as_int(v), imm))
#define SWZ_MAX(v, imm) \
  (v) = fmaxf(v, __int_as_float(__builtin_amdgcn_ds_swizzle(__float_as_int(v), imm)))

// ---- one-time converts ------------------------------------------------------
__global__ __launch_bounds__(256) void convert_x(const float* __restrict__ x,
                                                 bf16* __restrict__ x_bf) {
  const int gid = blockIdx.x * 256 + threadIdx.x;
  bf16x8 o;
#pragma unroll
  for (int j = 0; j < 8; ++j) o[j] = (bf16)x[(size_t)gid * 8 + j];
  *(bf16x8*)(x_bf + (size_t)gid * 8) = o;
}

// W (1024 x 4096 f32, orig cols) -> fragment tiles over permuted cols cx.
__global__ __launch_bounds__(256) void convert_wt(const float* __restrict__ W,
                                                  bf16* __restrict__ Wt) {
  const int gid = blockIdx.x * 256 + threadIdx.x;
  const int tile = gid >> 6, l = gid & 63;  // tile = tau*32 + kt
  const int tau = tile >> 5, kt = tile & 31;
  const int cx = tau * 16 + (l & 15);
  const int ht = cx >> 6, rem = cx & 63;
  const int co = (rem & 3) * HH + ht * 16 + (rem >> 2);  // g*1024 + h
  const int k0 = kt * 32 + (l >> 4) * 8;
  bf16x8 o;
#pragma unroll
  for (int j = 0; j < 8; ++j) o[j] = (bf16)W[(size_t)(k0 + j) * NOUT + co];
  *(bf16x8*)(Wt + (size_t)tile * 512 + l * 8) = o;
}

// A (256 x 1024 x 16 f32) -> At rows (n*16+p): At[n*16+p][h] = A[n][h][p], bf16.
__global__ __launch_bounds__(1024) void transpose_A(const float* __restrict__ A,
                                                    bf16* __restrict__ At) {
  __shared__ float lt[1024 * 17];  // padded vs bank conflicts
  const int n = blockIdx.x, u = threadIdx.x;
  const float* ar = A + ((size_t)n * HH + u) * 16;
#pragma unroll
  for (int q = 0; q < 4; ++q) {
    f32x4 v = *(const f32x4*)(ar + q * 4);
#pragma unroll
    for (int r = 0; r < 4; ++r) lt[u * 17 + q * 4 + r] = v[r];
  }
  __syncthreads();
  const int p = u >> 6, seg = u & 63;  // 16 h per thread
  bf16x8 o0, o1;
#pragma unroll
  for (int j = 0; j < 8; ++j) {
    o0[j] = (bf16)lt[(seg * 16 + j) * 17 + p];
    o1[j] = (bf16)lt[(seg * 16 + 8 + j) * 17 + p];
  }
  bf16* dst = At + (size_t)(n * 16 + p) * 1024 + seg * 16;
  *(bf16x8*)dst = o0;
  *(bf16x8*)(dst + 8) = o1;
}

// ---- 128x128 / BK=32 GEMM (m97 structure): C[M x 4096] = Am[M x 1024] @ Bt --
template <bool F32OUT>
__global__ __launch_bounds__(256, 3) void gemm128(const bf16* __restrict__ Am,
                                                  const bf16* __restrict__ Bt,
                                                  void* __restrict__ Cv) {
  __shared__ __align__(16) bf16 astg[2][8 * 512];  // 128r x 32k
  __shared__ __align__(16) bf16 bstg[2][8 * 512];  // 32k x 128c
  const int b = blockIdx.x;
  const int ct = b & 31, rt = b >> 5;
  const int tid = threadIdx.x, lane = tid & 63, wid = tid >> 6;
  const int wr = wid >> 1, wc = wid & 1;

  const bf16* gA[2];
  const bf16* gB[2];
  int lA[2], lB[2];
#pragma unroll
  for (int e = 0; e < 2; ++e) {
    const int mt = wid * 2 + e;  // A tile = 16 rows x 32 k
    gA[e] = Am + (size_t)(rt * 128 + mt * 16 + (lane & 15)) * 1024 + (lane >> 4) * 8;
    lA[e] = mt * 512;
    const int jt = wid * 2 + e;  // B tile tau = ct*8+jt, ktile advances with it
    gB[e] = Bt + ((size_t)(ct * 8 + jt) * 32) * 512 + lane * 8;
    lB[e] = jt * 512;
  }
  f32x4 acc[4][4];
#pragma unroll
  for (int i = 0; i < 4; ++i)
#pragma unroll
    for (int j = 0; j < 4; ++j) acc[i][j] = (f32x4){0, 0, 0, 0};

#pragma unroll
  for (int e = 0; e < 2; ++e) {
    gload_lds16(gA[e], &astg[0][lA[e]]);
    gload_lds16(gB[e], &bstg[0][lB[e]]);
  }
  for (int it = 0; it < 32; ++it) {
    __syncthreads();
    if (it < 31) {
#pragma unroll
      for (int e = 0; e < 2; ++e) {
        gload_lds16(gA[e] + (it + 1) * 32, &astg[(it + 1) & 1][lA[e]]);
        gload_lds16(gB[e] + (size_t)(it + 1) * 512, &bstg[(it + 1) & 1][lB[e]]);
      }
    }
    const bf16* ab = astg[it & 1];
    const bf16* bb = bstg[it & 1];
    bf16x8 af[4], bfr[4];
#pragma unroll
    for (int i = 0; i < 4; ++i) af[i] = *(const bf16x8*)(ab + (wr * 4 + i) * 512 + lane * 8);
#pragma unroll
    for (int j = 0; j < 4; ++j) bfr[j] = *(const bf16x8*)(bb + (wc * 4 + j) * 512 + lane * 8);
#pragma unroll
    for (int i = 0; i < 4; ++i)
#pragma unroll
      for (int j = 0; j < 4; ++j)
        acc[i][j] = __builtin_amdgcn_mfma_f32_16x16x32_bf16(af[i], bfr[j], acc[i][j], 0, 0, 0);
  }
  // C/D layout: col=lane&15, row=(lane>>4)*4+r [m89-verified]
#pragma unroll
  for (int i = 0; i < 4; ++i)
#pragma unroll
    for (int j = 0; j < 4; ++j) {
      const int row0 = rt * 128 + wr * 64 + i * 16 + (lane >> 4) * 4;
      const int col = ct * 128 + wc * 64 + j * 16 + (lane & 15);
#pragma unroll
      for (int r = 0; r < 4; ++r) {
        if (F32OUT) ((float*)Cv)[(size_t)(row0 + r) * NOUT + col] = acc[i][j][r];
        else        ((bf16*)Cv)[(size_t)(row0 + r) * NOUT + col] = (bf16)acc[i][j][r];
      }
    }
}

// ---- init: h0 = mean(A); c0 = h0; Aop0 = h0; seed s_part[0] -----------------
__global__ __launch_bounds__(1024) void init_kernel(const float* __restrict__ A,
                                                    float* __restrict__ c_ws,
                                                    bf16* __restrict__ Aop0,
                                                    float* __restrict__ s0) {
  __shared__ float h_sh[1024];
  __shared__ float scA[16], scB[16];
  const int n = (blockIdx.x & 7) * 32 + (blockIdx.x >> 3);
  const int u = threadIdx.x;
  const float* arow = A + ((size_t)n * HH + u) * 16;
  float h0 = 0.f;
#pragma unroll
  for (int p = 0; p < 16; ++p) h0 += arow[p];
  h0 *= 0.0625f;
  c_ws[(n << 10) + u] = h0;
  h_sh[u] = h0;
  Aop0[(n << 10) + u] = (bf16)h0;
  __syncthreads();
  const int lane = u & 63, w = u >> 6;  // wave w owns position p=w
  const float* ap = A + (size_t)n * (HH * 16) + w;
  float s = 0.f;
#pragma unroll
  for (int i = 0; i < 16; ++i) {
    const int idx = lane + 64 * i;
    s = fmaf(h_sh[idx], ap[(size_t)idx * 16], s);
  }
  SWZ_ADD(s, 0x041F); SWZ_ADD(s, 0x081F); SWZ_ADD(s, 0x101F);
  SWZ_ADD(s, 0x201F); SWZ_ADD(s, 0x401F);
  if (lane == 0) scA[w] = s;
  else if (lane == 32) scB[w] = s;
  __syncthreads();
  const int p = u >> 6, slot = u & 63;
  s0[((size_t)n * 16 + p) * 64 + slot] = (slot == 0) ? (scA[p] + scB[p]) : 0.f;
}

// ---- the per-step kernel: softmax(prev scores) + GEMM(h@Wh) + G-attn + cell
//      + next-step score partials. ONE launch per step. ----------------------
#define STEP_SMEM 69632
__global__ __launch_bounds__(1024, 4) void step_kernel(
    const bf16* __restrict__ Aop_cur, bf16* __restrict__ Aop_nxt,
    const bf16* __restrict__ Wh_t, const bf16* __restrict__ xWx,
    const float* __restrict__ G, const float* __restrict__ s_cur,
    float* __restrict__ s_nxt, const float* __restrict__ bias,
    const float* __restrict__ A, float* __restrict__ c_ws,
    float* __restrict__ out, const int t) {
  __shared__ __align__(16) char smem[STEP_SMEM];
  __shared__ float w_sh[1024];
  bf16* astg = (bf16*)smem;   // [kg][buf][8 tiles][512] = 64 KB
  float* red = (float*)smem;  // unions: gate partials, then score transpose

  const int b = blockIdx.x;
  const int xcd = b & 7, idx = b >> 3;
  const int ht = xcd * 8 + (idx & 7);  // [0,64): cx block [ht*64,+64)
  const int rt = idx >> 3;             // [0,4):  n block [rt*64,+64)
  const int tid = threadIdx.x, lane = tid & 63, wid = tid >> 6;
  const int kg = wid >> 2, ow = wid & 3, wr = ow >> 1, wc = ow & 1;

  // A staging pointers (wave stages 2 tiles of its kg)
  const bf16* gA[2];
  int lA[2];
#pragma unroll
  for (int e = 0; e < 2; ++e) {
    const int tl = ow * 2 + e, mt = tl >> 1, kt = tl & 1;
    gA[e] = Aop_cur + (size_t)(rt * 64 + mt * 16 + (lane & 15)) * 1024 +
            kg * 256 + kt * 32 + (lane >> 4) * 8;
    lA[e] = kg * 8192 + tl * 512;  // + buf*4096
  }
#pragma unroll
  for (int e = 0; e < 2; ++e) gload_lds16(gA[e], astg + lA[e]);

  // B pointers + it0 prefetch
  const bf16* gB[2][2];
#pragma unroll
  for (int j = 0; j < 2; ++j)
#pragma unroll
    for (int kk = 0; kk < 2; ++kk)
      gB[j][kk] = Wh_t + ((size_t)(ht * 4 + wc * 2 + j) * 32 + kg * 8 + kk) * 512 + lane * 8;
  bf16x8 bc00 = *(const bf16x8*)gB[0][0], bc01 = *(const bf16x8*)gB[0][1];
  bf16x8 bc10 = *(const bf16x8*)gB[1][0], bc11 = *(const bf16x8*)gB[1][1];

  // prologue: sum 64 score slots -> softmax over p (16-lane groups) -> w_sh
  {
    const int n_p = rt * 64 + (tid >> 4), p_p = tid & 15;
    const f32x4* sp4 = (const f32x4*)(s_cur + ((size_t)n_p * 16 + p_p) * 64);
    float ss = 0.f;
#pragma unroll
    for (int q = 0; q < 16; ++q) {
      f32x4 v = sp4[q];
      ss += v[0] + v[1] + v[2] + v[3];
    }
    ss *= 0.03125f;  // 1/sqrt(1024)
    float m = ss;
    SWZ_MAX(m, 0x041F); SWZ_MAX(m, 0x081F); SWZ_MAX(m, 0x101F); SWZ_MAX(m, 0x201F);
    const float e = expf(ss - m);
    float su = e;
    SWZ_ADD(su, 0x041F); SWZ_ADD(su, 0x081F); SWZ_ADD(su, 0x101F); SWZ_ADD(su, 0x201F);
    w_sh[tid] = e / su;
  }

  f32x4 a00 = {0, 0, 0, 0}, a01 = {0, 0, 0, 0}, a10 = {0, 0, 0, 0}, a11 = {0, 0, 0, 0};
  for (int it = 0; it < 4; ++it) {
    __syncthreads();  // buf(it&1) staged (vmcnt drained); prev readers done
    bf16x8 bn00, bn01, bn10, bn11;
    if (it < 3) {
#pragma unroll
      for (int e = 0; e < 2; ++e)
        gload_lds16(gA[e] + (it + 1) * 64, astg + lA[e] + ((it + 1) & 1) * 4096);
      bn00 = *(const bf16x8*)(gB[0][0] + (it + 1) * 1024);
      bn01 = *(const bf16x8*)(gB[0][1] + (it + 1) * 1024);
      bn10 = *(const bf16x8*)(gB[1][0] + (it + 1) * 1024);
      bn11 = *(const bf16x8*)(gB[1][1] + (it + 1) * 1024);
    }
    const bf16* ab = astg + kg * 8192 + (it & 1) * 4096;
#pragma unroll
    for (int kk = 0; kk < 2; ++kk) {
      const bf16x8 f0 = *(const bf16x8*)(ab + ((wr * 2 + 0) * 2 + kk) * 512 + lane * 8);
      const bf16x8 f1 = *(const bf16x8*)(ab + ((wr * 2 + 1) * 2 + kk) * 512 + lane * 8);
      const bf16x8 b0 = kk ? bc01 : bc00;
      const bf16x8 b1 = kk ? bc11 : bc10;
      a00 = __builtin_amdgcn_mfma_f32_16x16x32_bf16(f0, b0, a00, 0, 0, 0);
      a01 = __builtin_amdgcn_mfma_f32_16x16x32_bf16(f0, b1, a01, 0, 0, 0);
      a10 = __builtin_amdgcn_mfma_f32_16x16x32_bf16(f1, b0, a10, 0, 0, 0);
      a11 = __builtin_amdgcn_mfma_f32_16x16x32_bf16(f1, b1, a11, 0, 0, 0);
    }
    if (it < 3) { bc00 = bn00; bc01 = bn01; bc10 = bn10; bc11 = bn11; }
  }
  __syncthreads();  // astg dead -> red live

  // fragment -> red[(kg*64 + c)*68 + nn]; c in [0,64) == hl*4+g (cx order)
  {
    const int cb = kg * 64 + wc * 32 + (lane & 15);
    const int nb = wr * 32 + (lane >> 4) * 4;
    *(f32x4*)&red[(cb)*68 + nb] = a00;
    *(f32x4*)&red[(cb + 16) * 68 + nb] = a01;
    *(f32x4*)&red[(cb)*68 + nb + 16] = a10;
    *(f32x4*)&red[(cb + 16) * 68 + nb + 16] = a11;
  }
  __syncthreads();

  // ---- cell ----
  const int nloc = tid >> 4, hl = tid & 15;
  const int n = rt * 64 + nloc, h = ht * 16 + hl;
  f32x4 gv = {0, 0, 0, 0};
#pragma unroll
  for (int k2 = 0; k2 < 4; ++k2)
#pragma unroll
    for (int g = 0; g < 4; ++g) gv[g] += red[(k2 * 64 + hl * 4 + g) * 68 + nloc];
  // attention contribution: sum_p w[n,p] * G[n*16+p][ht*64+hl*4 .. +4]
  const float* Gp = G + ((size_t)n * 16) * NOUT + ht * 64 + hl * 4;
#pragma unroll
  for (int p = 0; p < 16; ++p) {
    const f32x4 q = *(const f32x4*)(Gp + (size_t)p * NOUT);
    const float wv = w_sh[nloc * 16 + p];
    gv[0] = fmaf(wv, q[0], gv[0]); gv[1] = fmaf(wv, q[1], gv[1]);
    gv[2] = fmaf(wv, q[2], gv[2]); gv[3] = fmaf(wv, q[3], gv[3]);
  }
  const bf16x4 xv = *(const bf16x4*)(xWx + ((size_t)(n * TS + t)) * NOUT + ht * 64 + hl * 4);
  const float ai = gv[0] + (float)xv[0] + bias[h];
  const float af = gv[1] + (float)xv[1] + bias[HH + h];
  const float ao = gv[2] + (float)xv[2] + bias[2 * HH + h];
  const float ag = gv[3] + (float)xv[3] + bias[3 * HH + h];
  const float cold = c_ws[(n << 10) + h];
  const float si = 1.f / (1.f + expf(-ai));
  const float sf = 1.f / (1.f + expf(-af));
  const float so = 1.f / (1.f + expf(-ao));
  const float cn = sf * cold + si * tanhf(ag);
  const float hn = so * tanhf(cn);
  c_ws[(n << 10) + h] = cn;
  out[((size_t)n * TS + t) * HH + h] = hn;
  Aop_nxt[(n << 10) + h] = (bf16)hn;

  if (t < TS - 1) {  // next-step score partials over this wg's 16 h
    __syncthreads();  // red gate-reads done -> reuse as transpose buffer
    const float* arow = A + ((size_t)n * HH + h) * 16;
#pragma unroll
    for (int q = 0; q < 4; ++q) {
      const f32x4 av = *(const f32x4*)(arow + q * 4);
#pragma unroll
      for (int r = 0; r < 4; ++r)
        red[(nloc * 16 + q * 4 + r) * 17 + hl] = hn * av[r];
    }
    __syncthreads();
    const float* r2 = &red[(nloc * 16 + hl) * 17];  // p = hl, sum over 16 h
    float s = 0.f;
#pragma unroll
    for (int q = 0; q < 16; ++q) s += r2[q];
    s_nxt[((size_t)n * 16 + hl) * 64 + ht] = s;
  }
}

// ---------------------------------------------------------------------------
// ws layout (bytes), total ~220 MiB:
//   [0, 67108864)            G (f32 4096x4096)   [transient overlay before
//                             g_gemm: x_bf at 0 (32 MiB), Wxt at 33554432]
//   [67108864, 75497472)     Wh_t   bf16 tiles (1024x4096, cx cols)
//   [75497472, 83886080)     Wat_t  bf16 tiles (1024x4096, cx cols)
//   [83886080, 92274688)     At     bf16 (4096x1024)
//   [92274688, 226492416)    xWx    bf16 (16384x4096, cx cols)
//   [226492416, 227016704)   Aop0   bf16 (256x1024)
//   [227016704, 227540992)   Aop1   bf16 (256x1024)
//   [227540992, 228589568)   s_part0 f32 (256x16x64)
//   [228589568, 229638144)   s_part1 f32 (256x16x64)
//   [229638144, 230686720)   c_ws   f32 (256x1024)
// ---------------------------------------------------------------------------
extern "C" void kernel_launch(void* const* d_in, const int* in_sizes, int n_in,
                              void* d_out, int out_size, void* d_ws, size_t ws_size,
                              hipStream_t stream) {
  const float* x     = (const float*)d_in[0];
  const float* A     = (const float*)d_in[1];
  const float* Wx    = (const float*)d_in[2];
  const float* Wh    = (const float*)d_in[3];
  const float* Wattn = (const float*)d_in[4];
  const float* bias  = (const float*)d_in[5];
  float* out = (float*)d_out;
  char* ws = (char*)d_ws;
  float* G     = (float*)(ws + 0);
  bf16* x_bf   = (bf16*)(ws + 0);          // transient (dead after xgemm)
  bf16* Wxt    = (bf16*)(ws + 33554432);   // transient (dead after xgemm)
  bf16* Wh_t   = (bf16*)(ws + 67108864);
  bf16* Wat_t  = (bf16*)(ws + 75497472);
  bf16* At     = (bf16*)(ws + 83886080);
  bf16* xWx    = (bf16*)(ws + 92274688);
  bf16* Aop[2] = {(bf16*)(ws + 226492416), (bf16*)(ws + 227016704)};
  float* sp[2] = {(float*)(ws + 227540992), (float*)(ws + 228589568)};
  float* c_ws  = (float*)(ws + 229638144);

  convert_x<<<8192, 256, 0, stream>>>(x, x_bf);
  convert_wt<<<2048, 256, 0, stream>>>(Wx, Wxt);
  convert_wt<<<2048, 256, 0, stream>>>(Wh, Wh_t);
  convert_wt<<<2048, 256, 0, stream>>>(Wattn, Wat_t);
  gemm128<false><<<4096, 256, 0, stream>>>(x_bf, Wxt, xWx);  // xWx = x @ Wx
  transpose_A<<<256, 1024, 0, stream>>>(A, At);
  gemm128<true><<<1024, 256, 0, stream>>>(At, Wat_t, G);     // G = A^T @ Wattn
  init_kernel<<<256, 1024, 0, stream>>>(A, c_ws, Aop[0], sp[0]);
  for (int t = 0; t < TS; ++t)
    step_kernel<<<256, 1024, 0, stream>>>(Aop[t & 1], Aop[(t + 1) & 1], Wh_t,
                                          xWx, G, sp[t & 1], sp[(t + 1) & 1],
                                          bias, A, c_ws, out, t);
}

// Round 9
// 1824.014 us; speedup vs baseline: 1.2423x; 1.1493x over previous
//
#include <hip/hip_runtime.h>

typedef __bf16 bf16;
typedef bf16 bf16x8 __attribute__((ext_vector_type(8)));
typedef bf16 bf16x4 __attribute__((ext_vector_type(4)));
typedef float f32x4 __attribute__((ext_vector_type(4)));

#define NB 256
#define TS 64
#define DD 1024
#define HH 1024
#define NOUT 4096

// Column permutation (all weight/preact tensors): cx = (h>>4)*64 + (h&15)*4 + g
// (original col co = g*1024 + h). wg "ht" owns cx in [ht*64,+64) = 16 h x 4
// gates -> finishes the LSTM cell locally; cell thread (n,hl) reads its 4
// gates as ONE bf16x4 at offset ht*64 + hl*4.
// Fragment tiles: 16col x 32k of 512 bf16; element (l,j): col=base+(l&15),
// k=kbase+(l>>4)*8+j (mfma_16x16x32 operand layout; linear LDS staging).

static __device__ __forceinline__ void gload_lds16(const void* g, void* l) {
  __builtin_amdgcn_global_load_lds(
      (const __attribute__((address_space(1))) void*)g,
      (__attribute__((address_space(3))) void*)l, 16, 0, 0);
}

#define SWZ_ADD(v, imm) \
  (v) += __int_as_float(__builtin_amdgcn_ds_swizzle(__float_as_int(v), imm))
#define SWZ_MAX(v, imm) \
  (v) = fmaxf(v, __int_as_float(__builtin_amdgcn_ds_swizzle(__float_as_int(v), imm)))

// ---- one-time converts ------------------------------------------------------
__global__ __launch_bounds__(256) void convert_bf(const float* __restrict__ in,
                                                  bf16* __restrict__ o) {
  const size_t gid = (size_t)blockIdx.x * 256 + threadIdx.x;
  bf16x8 v;
#pragma unroll
  for (int j = 0; j < 8; ++j) v[j] = (bf16)in[gid * 8 + j];
  *(bf16x8*)(o + gid * 8) = v;
}

// W (1024 x 4096 f32, orig cols) -> fragment tiles over permuted cols cx.
__global__ __launch_bounds__(256) void convert_wt(const float* __restrict__ W,
                                                  bf16* __restrict__ Wt) {
  const int gid = blockIdx.x * 256 + threadIdx.x;
  const int tile = gid >> 6, l = gid & 63;  // tile = tau*32 + kt
  const int tau = tile >> 5, kt = tile & 31;
  const int cx = tau * 16 + (l & 15);
  const int ht = cx >> 6, rem = cx & 63;
  const int co = (rem & 3) * HH + ht * 16 + (rem >> 2);  // g*1024 + h
  const int k0 = kt * 32 + (l >> 4) * 8;
  bf16x8 o;
#pragma unroll
  for (int j = 0; j < 8; ++j) o[j] = (bf16)W[(size_t)(k0 + j) * NOUT + co];
  *(bf16x8*)(Wt + (size_t)tile * 512 + l * 8) = o;
}

// A (256 x 1024 x 16 f32) -> At rows (n*16+p): At[n*16+p][h] = A[n][h][p], bf16.
__global__ __launch_bounds__(1024) void transpose_A(const float* __restrict__ A,
                                                    bf16* __restrict__ At) {
  __shared__ float lt[1024 * 17];
  const int n = blockIdx.x, u = threadIdx.x;
  const float* ar = A + ((size_t)n * HH + u) * 16;
#pragma unroll
  for (int q = 0; q < 4; ++q) {
    f32x4 v = *(const f32x4*)(ar + q * 4);
#pragma unroll
    for (int r = 0; r < 4; ++r) lt[u * 17 + q * 4 + r] = v[r];
  }
  __syncthreads();
  const int p = u >> 6, seg = u & 63;  // 16 h per thread
  bf16x8 o0, o1;
#pragma unroll
  for (int j = 0; j < 8; ++j) {
    o0[j] = (bf16)lt[(seg * 16 + j) * 17 + p];
    o1[j] = (bf16)lt[(seg * 16 + 8 + j) * 17 + p];
  }
  bf16* dst = At + (size_t)(n * 16 + p) * 1024 + seg * 16;
  *(bf16x8*)dst = o0;
  *(bf16x8*)(dst + 8) = o1;
}

// ---- 128x128 / BK=32 GEMM (m97 structure): C[M x 4096] = Am[M x 1024] @ Bt,
//      bf16 out ---------------------------------------------------------------
__global__ __launch_bounds__(256, 3) void gemm128(const bf16* __restrict__ Am,
                                                  const bf16* __restrict__ Bt,
                                                  bf16* __restrict__ C) {
  __shared__ __align__(16) bf16 astg[2][8 * 512];
  __shared__ __align__(16) bf16 bstg[2][8 * 512];
  const int b = blockIdx.x;
  const int ct = b & 31, rt = b >> 5;
  const int tid = threadIdx.x, lane = tid & 63, wid = tid >> 6;
  const int wr = wid >> 1, wc = wid & 1;

  const bf16* gA[2];
  const bf16* gB[2];
  int lA[2], lB[2];
#pragma unroll
  for (int e = 0; e < 2; ++e) {
    const int mt = wid * 2 + e;
    gA[e] = Am + (size_t)(rt * 128 + mt * 16 + (lane & 15)) * 1024 + (lane >> 4) * 8;
    lA[e] = mt * 512;
    gB[e] = Bt + ((size_t)(ct * 8 + mt) * 32) * 512 + lane * 8;
    lB[e] = mt * 512;
  }
  f32x4 acc[4][4];
#pragma unroll
  for (int i = 0; i < 4; ++i)
#pragma unroll
    for (int j = 0; j < 4; ++j) acc[i][j] = (f32x4){0, 0, 0, 0};

#pragma unroll
  for (int e = 0; e < 2; ++e) {
    gload_lds16(gA[e], &astg[0][lA[e]]);
    gload_lds16(gB[e], &bstg[0][lB[e]]);
  }
  for (int it = 0; it < 32; ++it) {
    __syncthreads();
    if (it < 31) {
#pragma unroll
      for (int e = 0; e < 2; ++e) {
        gload_lds16(gA[e] + (it + 1) * 32, &astg[(it + 1) & 1][lA[e]]);
        gload_lds16(gB[e] + (size_t)(it + 1) * 512, &bstg[(it + 1) & 1][lB[e]]);
      }
    }
    const bf16* ab = astg[it & 1];
    const bf16* bb = bstg[it & 1];
    bf16x8 af[4], bfr[4];
#pragma unroll
    for (int i = 0; i < 4; ++i) af[i] = *(const bf16x8*)(ab + (wr * 4 + i) * 512 + lane * 8);
#pragma unroll
    for (int j = 0; j < 4; ++j) bfr[j] = *(const bf16x8*)(bb + (wc * 4 + j) * 512 + lane * 8);
#pragma unroll
    for (int i = 0; i < 4; ++i)
#pragma unroll
      for (int j = 0; j < 4; ++j)
        acc[i][j] = __builtin_amdgcn_mfma_f32_16x16x32_bf16(af[i], bfr[j], acc[i][j], 0, 0, 0);
  }
  // C/D layout: col=lane&15, row=(lane>>4)*4+r [m89-verified]
#pragma unroll
  for (int i = 0; i < 4; ++i)
#pragma unroll
    for (int j = 0; j < 4; ++j) {
      const int row0 = rt * 128 + wr * 64 + i * 16 + (lane >> 4) * 4;
      const int col = ct * 128 + wc * 64 + j * 16 + (lane & 15);
#pragma unroll
      for (int r = 0; r < 4; ++r)
        C[(size_t)(row0 + r) * NOUT + col] = (bf16)acc[i][j][r];
    }
}

// ---- init: h0 = mean(A); c0 = h0; Aop0 = h0; seed s_part[0] -----------------
__global__ __launch_bounds__(1024) void init_kernel(const float* __restrict__ A,
                                                    float* __restrict__ c_ws,
                                                    bf16* __restrict__ Aop0,
                                                    float* __restrict__ s0) {
  __shared__ float h_sh[1024];
  __shared__ float scA[16], scB[16];
  const int n = (blockIdx.x & 7) * 32 + (blockIdx.x >> 3);
  const int u = threadIdx.x;
  const float* arow = A + ((size_t)n * HH + u) * 16;
  float h0 = 0.f;
#pragma unroll
  for (int p = 0; p < 16; ++p) h0 += arow[p];
  h0 *= 0.0625f;
  c_ws[(n << 10) + u] = h0;
  h_sh[u] = h0;
  Aop0[(n << 10) + u] = (bf16)h0;
  __syncthreads();
  const int lane = u & 63, w = u >> 6;  // wave w owns position p=w
  const float* ap = A + (size_t)n * (HH * 16) + w;
  float s = 0.f;
#pragma unroll
  for (int i = 0; i < 16; ++i) {
    const int idx = lane + 64 * i;
    s = fmaf(h_sh[idx], ap[(size_t)idx * 16], s);
  }
  SWZ_ADD(s, 0x041F); SWZ_ADD(s, 0x081F); SWZ_ADD(s, 0x101F);
  SWZ_ADD(s, 0x201F); SWZ_ADD(s, 0x401F);
  if (lane == 0) scA[w] = s;
  else if (lane == 32) scB[w] = s;
  __syncthreads();
  const int p = u >> 6, slot = u & 63;
  s0[((size_t)n * 16 + p) * 64 + slot] = (slot == 0) ? (scA[p] + scB[p]) : 0.f;
}

// ---- per-step kernel: softmax(prev scores) + GEMM(h@Wh) + G-attn + cell +
//      next-step score partials. ONE launch per step. ------------------------
#define STEP_SMEM 69632
__global__ __launch_bounds__(1024, 4) void step_kernel(
    const bf16* __restrict__ Aop_cur, bf16* __restrict__ Aop_nxt,
    const bf16* __restrict__ Wh_t, const bf16* __restrict__ xWx,
    const bf16* __restrict__ G, const float* __restrict__ s_cur,
    float* __restrict__ s_nxt, const float* __restrict__ bias,
    const bf16* __restrict__ A_bf, float* __restrict__ c_ws,
    float* __restrict__ out, const int t) {
  __shared__ __align__(16) char smem[STEP_SMEM];
  __shared__ float w_sh[1024];
  bf16* astg = (bf16*)smem;   // [kg][buf][8 tiles][512] = 64 KB
  float* red = (float*)smem;  // unions: gate partials, then score transpose

  const int b = blockIdx.x;
  const int xcd = b & 7, idx = b >> 3;
  const int ht = xcd * 8 + (idx & 7);  // [0,64): cx block [ht*64,+64)
  const int rt = idx >> 3;             // [0,4):  n block [rt*64,+64)
  const int tid = threadIdx.x, lane = tid & 63, wid = tid >> 6;
  const int kg = wid >> 2, ow = wid & 3, wr = ow >> 1, wc = ow & 1;
  const int nloc = tid >> 4, hl = tid & 15;
  const int n = rt * 64 + nloc, h = ht * 16 + hl;

  // A staging pointers (wave stages 2 tiles of its kg); issue buf0 now
  const bf16* gA[2];
  int lA[2];
#pragma unroll
  for (int e = 0; e < 2; ++e) {
    const int tl = ow * 2 + e, mt = tl >> 1, kt = tl & 1;
    gA[e] = Aop_cur + (size_t)(rt * 64 + mt * 16 + (lane & 15)) * 1024 +
            kg * 256 + kt * 32 + (lane >> 4) * 8;
    lA[e] = kg * 8192 + tl * 512;  // + buf*4096
  }
#pragma unroll
  for (int e = 0; e < 2; ++e) gload_lds16(gA[e], astg + lA[e]);

  // B pointers + it0 prefetch
  const bf16* gB[2][2];
#pragma unroll
  for (int j = 0; j < 2; ++j)
#pragma unroll
    for (int kk = 0; kk < 2; ++kk)
      gB[j][kk] = Wh_t + ((size_t)(ht * 4 + wc * 2 + j) * 32 + kg * 8 + kk) * 512 + lane * 8;
  bf16x8 bc00 = *(const bf16x8*)gB[0][0], bc01 = *(const bf16x8*)gB[0][1];
  bf16x8 bc10 = *(const bf16x8*)gB[1][0], bc11 = *(const bf16x8*)gB[1][1];

  // T14 early-issue: G rows (16 x bf16x4, static-indexed -> registers) + xWx.
  // Latency hides under the softmax prologue + GEMM phase.
  bf16x4 gq[16];
  {
    const bf16* Gp = G + ((size_t)n * 16) * NOUT + ht * 64 + hl * 4;
#pragma unroll
    for (int p = 0; p < 16; ++p) gq[p] = *(const bf16x4*)(Gp + (size_t)p * NOUT);
  }
  const bf16x4 xv = *(const bf16x4*)(xWx + ((size_t)(n * TS + t)) * NOUT + ht * 64 + hl * 4);

  // prologue: sum 64 score slots -> softmax over p (16-lane groups) -> w_sh
  {
    const f32x4* sp4 = (const f32x4*)(s_cur + ((size_t)(rt * 64 + (tid >> 4)) * 16 + (tid & 15)) * 64);
    float ss = 0.f;
#pragma unroll
    for (int q = 0; q < 16; ++q) {
      f32x4 v = sp4[q];
      ss += v[0] + v[1] + v[2] + v[3];
    }
    ss *= 0.03125f;  // 1/sqrt(1024)
    float m = ss;
    SWZ_MAX(m, 0x041F); SWZ_MAX(m, 0x081F); SWZ_MAX(m, 0x101F); SWZ_MAX(m, 0x201F);
    const float e = expf(ss - m);
    float su = e;
    SWZ_ADD(su, 0x041F); SWZ_ADD(su, 0x081F); SWZ_ADD(su, 0x101F); SWZ_ADD(su, 0x201F);
    w_sh[tid] = e / su;
  }

  f32x4 a00 = {0, 0, 0, 0}, a01 = {0, 0, 0, 0}, a10 = {0, 0, 0, 0}, a11 = {0, 0, 0, 0};
  for (int it = 0; it < 4; ++it) {
    __syncthreads();  // buf(it&1) staged (vmcnt drained); prev readers done
    bf16x8 bn00, bn01, bn10, bn11;
    if (it < 3) {
#pragma unroll
      for (int e = 0; e < 2; ++e)
        gload_lds16(gA[e] + (it + 1) * 64, astg + lA[e] + ((it + 1) & 1) * 4096);
      bn00 = *(const bf16x8*)(gB[0][0] + (it + 1) * 1024);
      bn01 = *(const bf16x8*)(gB[0][1] + (it + 1) * 1024);
      bn10 = *(const bf16x8*)(gB[1][0] + (it + 1) * 1024);
      bn11 = *(const bf16x8*)(gB[1][1] + (it + 1) * 1024);
    }
    const bf16* ab = astg + kg * 8192 + (it & 1) * 4096;
#pragma unroll
    for (int kk = 0; kk < 2; ++kk) {
      const bf16x8 f0 = *(const bf16x8*)(ab + ((wr * 2 + 0) * 2 + kk) * 512 + lane * 8);
      const bf16x8 f1 = *(const bf16x8*)(ab + ((wr * 2 + 1) * 2 + kk) * 512 + lane * 8);
      const bf16x8 b0 = kk ? bc01 : bc00;
      const bf16x8 b1 = kk ? bc11 : bc10;
      a00 = __builtin_amdgcn_mfma_f32_16x16x32_bf16(f0, b0, a00, 0, 0, 0);
      a01 = __builtin_amdgcn_mfma_f32_16x16x32_bf16(f0, b1, a01, 0, 0, 0);
      a10 = __builtin_amdgcn_mfma_f32_16x16x32_bf16(f1, b0, a10, 0, 0, 0);
      a11 = __builtin_amdgcn_mfma_f32_16x16x32_bf16(f1, b1, a11, 0, 0, 0);
    }
    if (it < 3) { bc00 = bn00; bc01 = bn01; bc10 = bn10; bc11 = bn11; }
  }
  __syncthreads();  // astg dead -> red live

  // fragment -> red[(kg*64 + c)*68 + nn]; c in [0,64) == hl*4+g (cx order)
  {
    const int cb = kg * 64 + wc * 32 + (lane & 15);
    const int nb = wr * 32 + (lane >> 4) * 4;
    *(f32x4*)&red[(cb)*68 + nb] = a00;
    *(f32x4*)&red[(cb + 16) * 68 + nb] = a01;
    *(f32x4*)&red[(cb)*68 + nb + 16] = a10;
    *(f32x4*)&red[(cb + 16) * 68 + nb + 16] = a11;
  }
  __syncthreads();

  // ---- cell ----
  f32x4 gv = {0, 0, 0, 0};
#pragma unroll
  for (int k2 = 0; k2 < 4; ++k2)
#pragma unroll
    for (int g = 0; g < 4; ++g) gv[g] += red[(k2 * 64 + hl * 4 + g) * 68 + nloc];
#pragma unroll
  for (int p = 0; p < 16; ++p) {
    const float wv = w_sh[nloc * 16 + p];
    gv[0] = fmaf(wv, (float)gq[p][0], gv[0]);
    gv[1] = fmaf(wv, (float)gq[p][1], gv[1]);
    gv[2] = fmaf(wv, (float)gq[p][2], gv[2]);
    gv[3] = fmaf(wv, (float)gq[p][3], gv[3]);
  }
  const float ai = gv[0] + (float)xv[0] + bias[h];
  const float af = gv[1] + (float)xv[1] + bias[HH + h];
  const float ao = gv[2] + (float)xv[2] + bias[2 * HH + h];
  const float ag = gv[3] + (float)xv[3] + bias[3 * HH + h];
  const float cold = c_ws[(n << 10) + h];
  const float si = 1.f / (1.f + expf(-ai));
  const float sf = 1.f / (1.f + expf(-af));
  const float so = 1.f / (1.f + expf(-ao));
  const float cn = sf * cold + si * tanhf(ag);
  const float hn = so * tanhf(cn);
  c_ws[(n << 10) + h] = cn;
  out[((size_t)n * TS + t) * HH + h] = hn;
  Aop_nxt[(n << 10) + h] = (bf16)hn;

  if (t < TS - 1) {  // next-step score partials over this wg's 16 h (bf16 A)
    __syncthreads();  // red gate-reads done -> reuse as transpose buffer
    const bf16* arow = A_bf + ((size_t)n * HH + h) * 16;
    const bf16x8 av0 = *(const bf16x8*)arow;
    const bf16x8 av1 = *(const bf16x8*)(arow + 8);
#pragma unroll
    for (int r = 0; r < 8; ++r) {
      red[(nloc * 16 + r) * 17 + hl] = hn * (float)av0[r];
      red[(nloc * 16 + 8 + r) * 17 + hl] = hn * (float)av1[r];
    }
    __syncthreads();
    const float* r2 = &red[(nloc * 16 + hl) * 17];  // p = hl, sum over 16 h
    float s = 0.f;
#pragma unroll
    for (int q = 0; q < 16; ++q) s += r2[q];
    s_nxt[((size_t)n * 16 + hl) * 64 + ht] = s;
  }
}

// ---------------------------------------------------------------------------
// ws layout (bytes), total ~236 MB of 256 MiB:
//   [0, 8388608)             Wh_t   bf16 tiles (1024x4096, cx cols)
//   [8388608, 16777216)      Wat_t  bf16 tiles (1024x4096, cx cols)
//   [16777216, 25165824)     At     bf16 (4096x1024)
//   [25165824, 33554432)     A_bf   bf16 (256x1024x16, original order)
//   [33554432, 167772160)    xWx    bf16 (16384x4096, cx cols)
//   [167772160, 201326592)   G      bf16 (4096x4096, cx cols)
//   [201326592, 234881024)   x_bf   bf16 (16384x1024)  [transient]
//   [234881024, 243269632)   Wxt    bf16 tiles         [transient]
//   [243269632, 243793920)   Aop0   bf16 (256x1024)
//   [243793920, 244318208)   Aop1   bf16 (256x1024)
//   [244318208, 245366784)   s0     f32 (256x16x64)
//   [245366784, 246415360)   s1     f32 (256x16x64)
//   [246415360, 247463936)   c_ws   f32 (256x1024)
// ---------------------------------------------------------------------------
extern "C" void kernel_launch(void* const* d_in, const int* in_sizes, int n_in,
                              void* d_out, int out_size, void* d_ws, size_t ws_size,
                              hipStream_t stream) {
  const float* x     = (const float*)d_in[0];
  const float* A     = (const float*)d_in[1];
  const float* Wx    = (const float*)d_in[2];
  const float* Wh    = (const float*)d_in[3];
  const float* Wattn = (const float*)d_in[4];
  const float* bias  = (const float*)d_in[5];
  float* out = (float*)d_out;
  char* ws = (char*)d_ws;
  bf16* Wh_t   = (bf16*)(ws + 0);
  bf16* Wat_t  = (bf16*)(ws + 8388608);
  bf16* At     = (bf16*)(ws + 16777216);
  bf16* A_bf   = (bf16*)(ws + 25165824);
  bf16* xWx    = (bf16*)(ws + 33554432);
  bf16* G      = (bf16*)(ws + 167772160);
  bf16* x_bf   = (bf16*)(ws + 201326592);
  bf16* Wxt    = (bf16*)(ws + 234881024);
  bf16* Aop[2] = {(bf16*)(ws + 243269632), (bf16*)(ws + 243793920)};
  float* sp[2] = {(float*)(ws + 244318208), (float*)(ws + 245366784)};
  float* c_ws  = (float*)(ws + 246415360);

  convert_bf<<<8192, 256, 0, stream>>>(x, x_bf);
  convert_bf<<<2048, 256, 0, stream>>>(A, A_bf);
  convert_wt<<<2048, 256, 0, stream>>>(Wx, Wxt);
  convert_wt<<<2048, 256, 0, stream>>>(Wh, Wh_t);
  convert_wt<<<2048, 256, 0, stream>>>(Wattn, Wat_t);
  gemm128<<<4096, 256, 0, stream>>>(x_bf, Wxt, xWx);  // xWx = x @ Wx
  transpose_A<<<256, 1024, 0, stream>>>(A, At);
  gemm128<<<1024, 256, 0, stream>>>(At, Wat_t, G);    // G = A^T @ Wattn (bf16)
  init_kernel<<<256, 1024, 0, stream>>>(A, c_ws, Aop[0], sp[0]);
  for (int t = 0; t < TS; ++t)
    step_kernel<<<256, 1024, 0, stream>>>(Aop[t & 1], Aop[(t + 1) & 1], Wh_t,
                                          xWx, G, sp[t & 1], sp[(t + 1) & 1],
                                          bias, A_bf, c_ws, out, t);
}

// Round 10
// 1770.360 us; speedup vs baseline: 1.2800x; 1.0303x over previous
//
#include <hip/hip_runtime.h>

typedef __bf16 bf16;
typedef bf16 bf16x8 __attribute__((ext_vector_type(8)));
typedef bf16 bf16x4 __attribute__((ext_vector_type(4)));
typedef float f32x4 __attribute__((ext_vector_type(4)));

#define NB 256
#define TS 64
#define DD 1024
#define HH 1024
#define NOUT 4096

// Column permutation (all weight/preact tensors): cx = (h>>4)*64 + (h&15)*4 + g
// (original col co = g*1024 + h). wg "ht" owns cx in [ht*64,+64) = 16 h x 4
// gates -> finishes the LSTM cell locally; cell thread (n,hl) reads its 4
// gates as ONE bf16x4 at offset ht*64 + hl*4.
// Fragment tiles: 16col x 32k of 512 bf16; element (l,j): col=base+(l&15),
// k=kbase+(l>>4)*8+j (mfma_16x16x32 operand layout; linear LDS staging).

static __device__ __forceinline__ void gload_lds16(const void* g, void* l) {
  __builtin_amdgcn_global_load_lds(
      (const __attribute__((address_space(1))) void*)g,
      (__attribute__((address_space(3))) void*)l, 16, 0, 0);
}

#define SWZ_ADD(v, imm) \
  (v) += __int_as_float(__builtin_amdgcn_ds_swizzle(__float_as_int(v), imm))
#define SWZ_MAX(v, imm) \
  (v) = fmaxf(v, __int_as_float(__builtin_amdgcn_ds_swizzle(__float_as_int(v), imm)))

// ---- one-time converts ------------------------------------------------------
__global__ __launch_bounds__(256) void convert_bf(const float* __restrict__ in,
                                                  bf16* __restrict__ o) {
  const size_t gid = (size_t)blockIdx.x * 256 + threadIdx.x;
  bf16x8 v;
#pragma unroll
  for (int j = 0; j < 8; ++j) v[j] = (bf16)in[gid * 8 + j];
  *(bf16x8*)(o + gid * 8) = v;
}

// W (1024 x 4096 f32, orig cols) -> fragment tiles over permuted cols cx.
__global__ __launch_bounds__(256) void convert_wt(const float* __restrict__ W,
                                                  bf16* __restrict__ Wt) {
  const int gid = blockIdx.x * 256 + threadIdx.x;
  const int tile = gid >> 6, l = gid & 63;  // tile = tau*32 + kt
  const int tau = tile >> 5, kt = tile & 31;
  const int cx = tau * 16 + (l & 15);
  const int ht = cx >> 6, rem = cx & 63;
  const int co = (rem & 3) * HH + ht * 16 + (rem >> 2);  // g*1024 + h
  const int k0 = kt * 32 + (l >> 4) * 8;
  bf16x8 o;
#pragma unroll
  for (int j = 0; j < 8; ++j) o[j] = (bf16)W[(size_t)(k0 + j) * NOUT + co];
  *(bf16x8*)(Wt + (size_t)tile * 512 + l * 8) = o;
}

// A (256 x 1024 x 16 f32) -> At rows (n*16+p): At[n*16+p][h] = A[n][h][p], bf16.
__global__ __launch_bounds__(1024) void transpose_A(const float* __restrict__ A,
                                                    bf16* __restrict__ At) {
  __shared__ float lt[1024 * 17];
  const int n = blockIdx.x, u = threadIdx.x;
  const float* ar = A + ((size_t)n * HH + u) * 16;
#pragma unroll
  for (int q = 0; q < 4; ++q) {
    f32x4 v = *(const f32x4*)(ar + q * 4);
#pragma unroll
    for (int r = 0; r < 4; ++r) lt[u * 17 + q * 4 + r] = v[r];
  }
  __syncthreads();
  const int p = u >> 6, seg = u & 63;  // 16 h per thread
  bf16x8 o0, o1;
#pragma unroll
  for (int j = 0; j < 8; ++j) {
    o0[j] = (bf16)lt[(seg * 16 + j) * 17 + p];
    o1[j] = (bf16)lt[(seg * 16 + 8 + j) * 17 + p];
  }
  bf16* dst = At + (size_t)(n * 16 + p) * 1024 + seg * 16;
  *(bf16x8*)dst = o0;
  *(bf16x8*)(dst + 8) = o1;
}

// ---- 128x128 / BK=32 GEMM (m97 structure), bf16 out, XCD-swizzled grid -----
// ct = (b&7)*4 + ((b>>3)&3): each XCD owns 4 col-tiles (1 MB B slice stays
// L2-resident); A rows served via L3 after first XCD touch.
__global__ __launch_bounds__(256, 3) void gemm128(const bf16* __restrict__ Am,
                                                  const bf16* __restrict__ Bt,
                                                  bf16* __restrict__ C) {
  __shared__ __align__(16) bf16 astg[2][8 * 512];
  __shared__ __align__(16) bf16 bstg[2][8 * 512];
  const int b = blockIdx.x;
  const int ct = (b & 7) * 4 + ((b >> 3) & 3);
  const int rt = b >> 5;
  const int tid = threadIdx.x, lane = tid & 63, wid = tid >> 6;
  const int wr = wid >> 1, wc = wid & 1;

  const bf16* gA[2];
  const bf16* gB[2];
  int lA[2], lB[2];
#pragma unroll
  for (int e = 0; e < 2; ++e) {
    const int mt = wid * 2 + e;
    gA[e] = Am + (size_t)(rt * 128 + mt * 16 + (lane & 15)) * 1024 + (lane >> 4) * 8;
    lA[e] = mt * 512;
    gB[e] = Bt + ((size_t)(ct * 8 + mt) * 32) * 512 + lane * 8;
    lB[e] = mt * 512;
  }
  f32x4 acc[4][4];
#pragma unroll
  for (int i = 0; i < 4; ++i)
#pragma unroll
    for (int j = 0; j < 4; ++j) acc[i][j] = (f32x4){0, 0, 0, 0};

#pragma unroll
  for (int e = 0; e < 2; ++e) {
    gload_lds16(gA[e], &astg[0][lA[e]]);
    gload_lds16(gB[e], &bstg[0][lB[e]]);
  }
  for (int it = 0; it < 32; ++it) {
    __syncthreads();
    if (it < 31) {
#pragma unroll
      for (int e = 0; e < 2; ++e) {
        gload_lds16(gA[e] + (it + 1) * 32, &astg[(it + 1) & 1][lA[e]]);
        gload_lds16(gB[e] + (size_t)(it + 1) * 512, &bstg[(it + 1) & 1][lB[e]]);
      }
    }
    const bf16* ab = astg[it & 1];
    const bf16* bb = bstg[it & 1];
    bf16x8 af[4], bfr[4];
#pragma unroll
    for (int i = 0; i < 4; ++i) af[i] = *(const bf16x8*)(ab + (wr * 4 + i) * 512 + lane * 8);
#pragma unroll
    for (int j = 0; j < 4; ++j) bfr[j] = *(const bf16x8*)(bb + (wc * 4 + j) * 512 + lane * 8);
#pragma unroll
    for (int i = 0; i < 4; ++i)
#pragma unroll
      for (int j = 0; j < 4; ++j)
        acc[i][j] = __builtin_amdgcn_mfma_f32_16x16x32_bf16(af[i], bfr[j], acc[i][j], 0, 0, 0);
  }
  // C/D layout: col=lane&15, row=(lane>>4)*4+r [m89-verified]
#pragma unroll
  for (int i = 0; i < 4; ++i)
#pragma unroll
    for (int j = 0; j < 4; ++j) {
      const int row0 = rt * 128 + wr * 64 + i * 16 + (lane >> 4) * 4;
      const int col = ct * 128 + wc * 64 + j * 16 + (lane & 15);
#pragma unroll
      for (int r = 0; r < 4; ++r)
        C[(size_t)(row0 + r) * NOUT + col] = (bf16)acc[i][j][r];
    }
}

// ---- init: h0 = mean(A); c0 = h0; Aop0 = h0; seed s_part[0] -----------------
__global__ __launch_bounds__(1024) void init_kernel(const float* __restrict__ A,
                                                    float* __restrict__ c_ws,
                                                    bf16* __restrict__ Aop0,
                                                    float* __restrict__ s0) {
  __shared__ float h_sh[1024];
  __shared__ float scA[16], scB[16];
  const int n = (blockIdx.x & 7) * 32 + (blockIdx.x >> 3);
  const int u = threadIdx.x;
  const float* arow = A + ((size_t)n * HH + u) * 16;
  float h0 = 0.f;
#pragma unroll
  for (int p = 0; p < 16; ++p) h0 += arow[p];
  h0 *= 0.0625f;
  c_ws[(n << 10) + u] = h0;
  h_sh[u] = h0;
  Aop0[(n << 10) + u] = (bf16)h0;
  __syncthreads();
  const int lane = u & 63, w = u >> 6;  // wave w owns position p=w
  const float* ap = A + (size_t)n * (HH * 16) + w;
  float s = 0.f;
#pragma unroll
  for (int i = 0; i < 16; ++i) {
    const int idx = lane + 64 * i;
    s = fmaf(h_sh[idx], ap[(size_t)idx * 16], s);
  }
  SWZ_ADD(s, 0x041F); SWZ_ADD(s, 0x081F); SWZ_ADD(s, 0x101F);
  SWZ_ADD(s, 0x201F); SWZ_ADD(s, 0x401F);
  if (lane == 0) scA[w] = s;
  else if (lane == 32) scB[w] = s;
  __syncthreads();
  const int p = u >> 6, slot = u & 63;
  s0[((size_t)n * 16 + p) * 64 + slot] = (slot == 0) ? (scA[p] + scB[p]) : 0.f;
}

// ---- per-step kernel: softmax(prev scores) + GEMM(h@Wh) + G-attn + cell +
//      next-step score partials. 512 wgs x 512 threads -> 2 wgs/CU so the
//      barrier groups of co-resident wgs overlap each other's drains. -------
#define STEP_SMEM 36864  // max(A-staging 32768, red 4*64*36*4 = 36864)
__global__ __launch_bounds__(512, 4) void step_kernel(
    const bf16* __restrict__ Aop_cur, bf16* __restrict__ Aop_nxt,
    const bf16* __restrict__ Wh_t, const bf16* __restrict__ xWx,
    const bf16* __restrict__ G, const float* __restrict__ s_cur,
    float* __restrict__ s_nxt, const float* __restrict__ bias,
    const bf16* __restrict__ A_bf, float* __restrict__ c_ws,
    float* __restrict__ out, const int t) {
  __shared__ __align__(16) char smem[STEP_SMEM];
  __shared__ float w_sh[512];
  bf16* astg = (bf16*)smem;   // [kg][buf][4 tiles][512] = 32 KB
  float* red = (float*)smem;  // [kg*64+c][36] f32 (union after K-loop)

  const int b = blockIdx.x;
  const int xcd = b & 7;
  const int ht = xcd * 8 + ((b >> 3) & 7);  // [0,64): cx block [ht*64,+64)
  const int rt = b >> 6;                    // [0,8):  n block [rt*32,+32)
  const int tid = threadIdx.x, lane = tid & 63, wid = tid >> 6;  // 8 waves
  const int kg = wid >> 1, ow = wid & 1;    // 4 K-groups x 2 col-half waves
  const int nloc = tid >> 4, hl = tid & 15; // 32 x 16
  const int n = rt * 32 + nloc, h = ht * 16 + hl;

  // A staging: wave (kg,ow) stages tiles tl = ow*2+e (mt=tl>>1, kt=tl&1)
  const bf16* gA[2];
  int lA[2];
#pragma unroll
  for (int e = 0; e < 2; ++e) {
    const int tl = ow * 2 + e, mt = tl >> 1, kt = tl & 1;
    gA[e] = Aop_cur + (size_t)(rt * 32 + mt * 16 + (lane & 15)) * 1024 +
            kg * 256 + kt * 32 + (lane >> 4) * 8;
    lA[e] = kg * 4096 + tl * 512;  // + buf*2048
  }
#pragma unroll
  for (int e = 0; e < 2; ++e) gload_lds16(gA[e], astg + lA[e]);

  // B pointers + it0 prefetch (cols: taus ht*4 + ow*2 + j)
  const bf16* gB[2][2];
#pragma unroll
  for (int j = 0; j < 2; ++j)
#pragma unroll
    for (int kk = 0; kk < 2; ++kk)
      gB[j][kk] = Wh_t + ((size_t)(ht * 4 + ow * 2 + j) * 32 + kg * 8 + kk) * 512 + lane * 8;
  bf16x8 bc00 = *(const bf16x8*)gB[0][0], bc01 = *(const bf16x8*)gB[0][1];
  bf16x8 bc10 = *(const bf16x8*)gB[1][0], bc11 = *(const bf16x8*)gB[1][1];

  // T14 early-issue: G rows (16 x bf16x4, static indices -> registers) + xWx
  bf16x4 gq[16];
  {
    const bf16* Gp = G + ((size_t)n * 16) * NOUT + ht * 64 + hl * 4;
#pragma unroll
    for (int p = 0; p < 16; ++p) gq[p] = *(const bf16x4*)(Gp + (size_t)p * NOUT);
  }
  const bf16x4 xv = *(const bf16x4*)(xWx + ((size_t)(n * TS + t)) * NOUT + ht * 64 + hl * 4);

  // prologue: sum 64 score slots -> softmax over p (16-lane groups) -> w_sh
  // thread = one (n,p) pair: n = rt*32+nloc, p = hl
  {
    const f32x4* sp4 = (const f32x4*)(s_cur + ((size_t)n * 16 + hl) * 64);
    float ss = 0.f;
#pragma unroll
    for (int q = 0; q < 16; ++q) {
      f32x4 v = sp4[q];
      ss += v[0] + v[1] + v[2] + v[3];
    }
    ss *= 0.03125f;  // 1/sqrt(1024)
    float m = ss;
    SWZ_MAX(m, 0x041F); SWZ_MAX(m, 0x081F); SWZ_MAX(m, 0x101F); SWZ_MAX(m, 0x201F);
    const float e = expf(ss - m);
    float su = e;
    SWZ_ADD(su, 0x041F); SWZ_ADD(su, 0x081F); SWZ_ADD(su, 0x101F); SWZ_ADD(su, 0x201F);
    w_sh[tid] = e / su;
  }

  f32x4 a00 = {0, 0, 0, 0}, a01 = {0, 0, 0, 0}, a10 = {0, 0, 0, 0}, a11 = {0, 0, 0, 0};
  for (int it = 0; it < 4; ++it) {
    __syncthreads();  // buf(it&1) staged (vmcnt drained); prev readers done
    bf16x8 bn00, bn01, bn10, bn11;
    if (it < 3) {
#pragma unroll
      for (int e = 0; e < 2; ++e)
        gload_lds16(gA[e] + (it + 1) * 64, astg + lA[e] + ((it + 1) & 1) * 2048);
      bn00 = *(const bf16x8*)(gB[0][0] + (it + 1) * 1024);
      bn01 = *(const bf16x8*)(gB[0][1] + (it + 1) * 1024);
      bn10 = *(const bf16x8*)(gB[1][0] + (it + 1) * 1024);
      bn11 = *(const bf16x8*)(gB[1][1] + (it + 1) * 1024);
    }
    const bf16* ab = astg + kg * 4096 + (it & 1) * 2048;
#pragma unroll
    for (int kk = 0; kk < 2; ++kk) {
      const bf16x8 f0 = *(const bf16x8*)(ab + (0 * 2 + kk) * 512 + lane * 8);
      const bf16x8 f1 = *(const bf16x8*)(ab + (1 * 2 + kk) * 512 + lane * 8);
      const bf16x8 b0 = kk ? bc01 : bc00;
      const bf16x8 b1 = kk ? bc11 : bc10;
      a00 = __builtin_amdgcn_mfma_f32_16x16x32_bf16(f0, b0, a00, 0, 0, 0);
      a01 = __builtin_amdgcn_mfma_f32_16x16x32_bf16(f0, b1, a01, 0, 0, 0);
      a10 = __builtin_amdgcn_mfma_f32_16x16x32_bf16(f1, b0, a10, 0, 0, 0);
      a11 = __builtin_amdgcn_mfma_f32_16x16x32_bf16(f1, b1, a11, 0, 0, 0);
    }
    if (it < 3) { bc00 = bn00; bc01 = bn01; bc10 = bn10; bc11 = bn11; }
  }
  __syncthreads();  // astg dead -> red live

  // fragment -> red[(kg*64 + c)*36 + nn]; c = ow*32 + j*16 + (lane&15)
  {
    const int cb = kg * 64 + ow * 32 + (lane & 15);
    const int nb = (lane >> 4) * 4;
    *(f32x4*)&red[(cb)*36 + nb] = a00;           // i=0, j=0
    *(f32x4*)&red[(cb + 16) * 36 + nb] = a01;    // i=0, j=1
    *(f32x4*)&red[(cb)*36 + nb + 16] = a10;      // i=1, j=0
    *(f32x4*)&red[(cb + 16) * 36 + nb + 16] = a11;
  }
  __syncthreads();

  // ---- cell ----
  f32x4 gv = {0, 0, 0, 0};
#pragma unroll
  for (int k2 = 0; k2 < 4; ++k2)
#pragma unroll
    for (int g = 0; g < 4; ++g) gv[g] += red[(k2 * 64 + hl * 4 + g) * 36 + nloc];
#pragma unroll
  for (int p = 0; p < 16; ++p) {
    const float wv = w_sh[nloc * 16 + p];
    gv[0] = fmaf(wv, (float)gq[p][0], gv[0]);
    gv[1] = fmaf(wv, (float)gq[p][1], gv[1]);
    gv[2] = fmaf(wv, (float)gq[p][2], gv[2]);
    gv[3] = fmaf(wv, (float)gq[p][3], gv[3]);
  }
  const float ai = gv[0] + (float)xv[0] + bias[h];
  const float af = gv[1] + (float)xv[1] + bias[HH + h];
  const float ao = gv[2] + (float)xv[2] + bias[2 * HH + h];
  const float ag = gv[3] + (float)xv[3] + bias[3 * HH + h];
  const float cold = c_ws[(n << 10) + h];
  const float si = 1.f / (1.f + expf(-ai));
  const float sf = 1.f / (1.f + expf(-af));
  const float so = 1.f / (1.f + expf(-ao));
  const float cn = sf * cold + si * tanhf(ag);
  const float hn = so * tanhf(cn);
  c_ws[(n << 10) + h] = cn;
  out[((size_t)n * TS + t) * HH + h] = hn;
  Aop_nxt[(n << 10) + h] = (bf16)hn;

  if (t < TS - 1) {  // next-step score partials over this wg's 16 h (bf16 A)
    __syncthreads();  // red gate-reads done -> reuse as transpose buffer
    const bf16* arow = A_bf + ((size_t)n * HH + h) * 16;
    const bf16x8 av0 = *(const bf16x8*)arow;
    const bf16x8 av1 = *(const bf16x8*)(arow + 8);
#pragma unroll
    for (int r = 0; r < 8; ++r) {
      red[(nloc * 16 + r) * 17 + hl] = hn * (float)av0[r];
      red[(nloc * 16 + 8 + r) * 17 + hl] = hn * (float)av1[r];
    }
    __syncthreads();
    const float* r2 = &red[(nloc * 16 + hl) * 17];  // p = hl, sum over 16 h
    float s = 0.f;
#pragma unroll
    for (int q = 0; q < 16; ++q) s += r2[q];
    s_nxt[((size_t)n * 16 + hl) * 64 + ht] = s;
  }
}

// ---------------------------------------------------------------------------
// ws layout (bytes), total ~236 MB of 256 MiB:
//   [0, 8388608)             Wh_t   bf16 tiles (1024x4096, cx cols)
//   [8388608, 16777216)      Wat_t  bf16 tiles (1024x4096, cx cols)
//   [16777216, 25165824)     At     bf16 (4096x1024)
//   [25165824, 33554432)     A_bf   bf16 (256x1024x16, original order)
//   [33554432, 167772160)    xWx    bf16 (16384x4096, cx cols)
//   [167772160, 201326592)   G      bf16 (4096x4096, cx cols)
//   [201326592, 234881024)   x_bf   bf16 (16384x1024)  [transient]
//   [234881024, 243269632)   Wxt    bf16 tiles         [transient]
//   [243269632, 243793920)   Aop0   bf16 (256x1024)
//   [243793920, 244318208)   Aop1   bf16 (256x1024)
//   [244318208, 245366784)   s0     f32 (256x16x64)
//   [245366784, 246415360)   s1     f32 (256x16x64)
//   [246415360, 247463936)   c_ws   f32 (256x1024)
// ---------------------------------------------------------------------------
extern "C" void kernel_launch(void* const* d_in, const int* in_sizes, int n_in,
                              void* d_out, int out_size, void* d_ws, size_t ws_size,
                              hipStream_t stream) {
  const float* x     = (const float*)d_in[0];
  const float* A     = (const float*)d_in[1];
  const float* Wx    = (const float*)d_in[2];
  const float* Wh    = (const float*)d_in[3];
  const float* Wattn = (const float*)d_in[4];
  const float* bias  = (const float*)d_in[5];
  float* out = (float*)d_out;
  char* ws = (char*)d_ws;
  bf16* Wh_t   = (bf16*)(ws + 0);
  bf16* Wat_t  = (bf16*)(ws + 8388608);
  bf16* At     = (bf16*)(ws + 16777216);
  bf16* A_bf   = (bf16*)(ws + 25165824);
  bf16* xWx    = (bf16*)(ws + 33554432);
  bf16* G      = (bf16*)(ws + 167772160);
  bf16* x_bf   = (bf16*)(ws + 201326592);
  bf16* Wxt    = (bf16*)(ws + 234881024);
  bf16* Aop[2] = {(bf16*)(ws + 243269632), (bf16*)(ws + 243793920)};
  float* sp[2] = {(float*)(ws + 244318208), (float*)(ws + 245366784)};
  float* c_ws  = (float*)(ws + 246415360);

  convert_bf<<<8192, 256, 0, stream>>>(x, x_bf);
  convert_bf<<<2048, 256, 0, stream>>>(A, A_bf);
  convert_wt<<<2048, 256, 0, stream>>>(Wx, Wxt);
  convert_wt<<<2048, 256, 0, stream>>>(Wh, Wh_t);
  convert_wt<<<2048, 256, 0, stream>>>(Wattn, Wat_t);
  gemm128<<<4096, 256, 0, stream>>>(x_bf, Wxt, xWx);  // xWx = x @ Wx
  transpose_A<<<256, 1024, 0, stream>>>(A, At);
  gemm128<<<1024, 256, 0, stream>>>(At, Wat_t, G);    // G = A^T @ Wattn (bf16)
  init_kernel<<<256, 1024, 0, stream>>>(A, c_ws, Aop[0], sp[0]);
  for (int t = 0; t < TS; ++t)
    step_kernel<<<512, 512, 0, stream>>>(Aop[t & 1], Aop[(t + 1) & 1], Wh_t,
                                         xWx, G, sp[t & 1], sp[(t + 1) & 1],
                                         bias, A_bf, c_ws, out, t);
}